// Round 11
// baseline (205.364 us; speedup 1.0000x reference)
//
#include <hip/hip_runtime.h>

#define CDIM 256
#define HW   1024
#define NPIX 65536
#define KDIM 1024
#define TAU  1.0f
#define RB   4
#define SWZ(c) (((c) & 31) ^ (((c) >> 3) & 24))

using bf16x8 = __attribute__((ext_vector_type(8))) short;
using f32x4  = __attribute__((ext_vector_type(4))) float;
typedef unsigned int u32;

static __device__ __forceinline__ unsigned short f2bf(float v) {
    union { float f; unsigned u; } a; a.f = v;
    unsigned u = a.u;
    u += 0x7fffu + ((u >> 16) & 1u);   // RTN
    return (unsigned short)(u >> 16);
}

static __device__ __forceinline__ void gload_lds16(const void* g, void* s) {
    __builtin_amdgcn_global_load_lds(
        (const __attribute__((address_space(1))) u32*)g,
        (__attribute__((address_space(3))) u32*)s,
        16, 0, 0);
}

static __device__ __forceinline__ u32 fbits(float f) {
    union { float f; u32 u; } a; a.f = f; return a.u;
}
static __device__ __forceinline__ float bitsf(u32 u) {
    union { u32 u; float f; } a; a.u = u; return a.f;
}

// -------- ee[k] = sum_c embed[c][k]^2 (exact) ; eeb = ee + 2048 (key bias) --------
__global__ void ee_kernel(const float* __restrict__ embed, float* __restrict__ ee,
                          float* __restrict__ eeb) {
    int k = blockIdx.x * 256 + threadIdx.x;
    float s = 0.f;
#pragma unroll 8
    for (int c = 0; c < CDIM; ++c) {
        float v = embed[c * KDIM + k];
        s += v * v;
    }
    ee[k] = s;
    eeb[k] = s + 2048.0f;
}

// -------- embedT[k][c] = embed[c][k] (fp32 transpose, 32x32 LDS tiles) --------
__global__ void transpose_e(const float* __restrict__ embed, float* __restrict__ embedT) {
    __shared__ float tl[32][33];
    const int t = threadIdx.x;
    const int j = t & 31, r = t >> 5;
    const int k0 = (blockIdx.x & 31) * 32;
    const int c0 = (blockIdx.x >> 5) * 32;
#pragma unroll
    for (int rr = 0; rr < 4; ++rr) {
        int c = r * 4 + rr;
        tl[c][j] = embed[(size_t)(c0 + c) * KDIM + k0 + j];
    }
    __syncthreads();
#pragma unroll
    for (int rr = 0; rr < 4; ++rr) {
        int k = r * 4 + rr;
        embedT[(size_t)(k0 + k) * CDIM + c0 + j] = tl[j][k];
    }
}

// -------- bf16(-2*embed) in MFMA B-fragment order --------
// frag f = ((nt*2+nh)*8 + ks)*4 + nf; lane l elem j:
//   B[k = ks*32 + (l>>4)*8 + j][n = nt*128 + (nh*4+nf)*16 + (l&15)]
__global__ void prep_e(const float* __restrict__ embed, short* __restrict__ e_hi) {
    int tid = blockIdx.x * 256 + threadIdx.x;   // 32768
    int l  = tid & 63;
    int f  = tid >> 6;            // 0..511
    int nf = f & 3;
    int ks = (f >> 2) & 7;
    int nh = (f >> 5) & 1;
    int nt = f >> 6;
    int n  = nt * 128 + (nh * 4 + nf) * 16 + (l & 15);
    int c0 = ks * 32 + (l >> 4) * 8;
    bf16x8 h8;
#pragma unroll
    for (int j = 0; j < 8; ++j)
        h8[j] = (short)f2bf(-2.0f * embed[(c0 + j) * KDIM + n]);
    *(bf16x8*)&e_hi[(size_t)tid * 8] = h8;
}

// -------- main screen: 128-px tiles (32 px/wave), K-split x4 (HIGH bits), packed keys --------
__launch_bounds__(256, 4)
__global__ void vq_gemm(const float* __restrict__ x, const short* __restrict__ e_hi,
                        const float* __restrict__ eeb,
                        float* __restrict__ hv1, float* __restrict__ hv2,
                        int* __restrict__ hidx) {
    __shared__ short Bs[2][8192];    // 2 x 16 KB (32 codes x 256 ch)
    const int t  = threadIdx.x;
    const int l  = t & 63;
    const int w  = t >> 6;
    const int lr = l & 15;
    const int lg = l >> 4;
    const int tile    = blockIdx.x & 511;       // 0..511 (128-px tiles)
    const int quarter = blockIdx.x >> 9;        // HIGH bits: stride 512 % 8 == 0 -> same XCD
    const int px0 = tile * 128 + w * 32;        // wave's 32 pixels
    const int b   = px0 >> 10;
    const int p0  = px0 & 1023;
    const float* xb = x + (size_t)b * CDIM * HW;

    const int c_first = quarter * 8;
    // stage chunk c slab s=w*4+i: src frag = ((c>>2)*2+((c>>1)&1))*32 + (c&1)*2 + (s>>1)*4 + (s&1)
    {
        const int slab = w * 4;
        const char* srcb = (const char*)e_hi +
            (size_t)(((c_first >> 2) * 2 + ((c_first >> 1) & 1)) * 32 + (c_first & 1) * 2) * 1024 + l * 16;
        char* dstb = (char*)&Bs[0][0] + (size_t)slab * 1024 + l * 16;
#pragma unroll
        for (int i = 0; i < 4; ++i) {
            int s = slab + i;
            gload_lds16(srcb + (size_t)((s >> 1) * 4 + (s & 1)) * 1024, dstb + (size_t)i * 1024);
        }
    }

    // ---- load + convert A fragments (32 px x 256 ch -> 16 frags = 64 VGPR) ----
    bf16x8 a[2][8];
#pragma unroll
    for (int mf = 0; mf < 2; ++mf) {
#pragma unroll
        for (int ks = 0; ks < 8; ++ks) {
            const float* p = xb + (size_t)(ks * 32 + lg * 8) * HW + p0 + mf * 16 + lr;
            float v[8];
#pragma unroll
            for (int j = 0; j < 8; ++j) v[j] = p[(size_t)j * HW];
#pragma unroll
            for (int j = 0; j < 8; ++j) a[mf][ks][j] = (short)f2bf(v[j]);
        }
    }

    // packed keys: (bits(dist+2048) & ~1023) | code_idx  (uint-monotonic, idx tie-break free)
    u32 min1k[8], min2k[8];
#pragma unroll
    for (int r = 0; r < 8; ++r) { min1k[r] = 0xFFFFFFFFu; min2k[r] = 0xFFFFFFFFu; }

    __syncthreads();   // chunk 0 staged

    for (int cc = 0; cc < 8; ++cc) {
        const int c   = c_first + cc;
        const int cur = cc & 1;
        if (cc < 7) {   // prefetch next chunk into the other buffer
            const int cn = c + 1;
            const int slab = w * 4;
            const char* srcb = (const char*)e_hi +
                (size_t)(((cn >> 2) * 2 + ((cn >> 1) & 1)) * 32 + (cn & 1) * 2) * 1024 + l * 16;
            char* dstb = (char*)&Bs[cur ^ 1][0] + (size_t)slab * 1024 + l * 16;
#pragma unroll
            for (int i = 0; i < 4; ++i) {
                int s = slab + i;
                gload_lds16(srcb + (size_t)((s >> 1) * 4 + (s & 1)) * 1024, dstb + (size_t)i * 1024);
            }
        }

        f32x4 acc[2][2];
#pragma unroll
        for (int mf = 0; mf < 2; ++mf)
#pragma unroll
            for (int nfi = 0; nfi < 2; ++nfi)
                acc[mf][nfi] = (f32x4){0.f, 0.f, 0.f, 0.f};

#pragma unroll
        for (int ks = 0; ks < 8; ++ks) {
#pragma unroll
            for (int nfi = 0; nfi < 2; ++nfi) {
                bf16x8 bh = *(const bf16x8*)&Bs[cur][((ks * 2 + nfi) * 64 + l) * 8];
#pragma unroll
                for (int mf = 0; mf < 2; ++mf)
                    acc[mf][nfi] = __builtin_amdgcn_mfma_f32_16x16x32_bf16(a[mf][ks], bh, acc[mf][nfi], 0, 0, 0);
            }
        }

        // fold chunk into running packed (min1, min2)
#pragma unroll
        for (int nfi = 0; nfi < 2; ++nfi) {
            const int kg = c * 32 + nfi * 16 + lr;
            const float ebv = eeb[kg];
#pragma unroll
            for (int mf = 0; mf < 2; ++mf)
#pragma unroll
                for (int j = 0; j < 4; ++j) {
                    const int r = mf * 4 + j;
                    u32 key = (fbits(acc[mf][nfi][j] + ebv) & 0xFFFFFC00u) | (u32)kg;
                    min2k[r] = min(min2k[r], max(key, min1k[r]));
                    min1k[r] = min(min1k[r], key);
                }
        }
        __syncthreads();   // next chunk landed + buffer swap
    }

    // ---- reduce across the 16 lanes (lr) sharing each pixel row ----
#pragma unroll
    for (int r = 0; r < 8; ++r) {
        u32 k1 = min1k[r], k2 = min2k[r];
#pragma unroll
        for (int mask = 1; mask < 16; mask <<= 1) {
            u32 ok1 = (u32)__shfl_xor((int)k1, mask, 64);
            u32 ok2 = (u32)__shfl_xor((int)k2, mask, 64);
            k2 = min(min(k2, ok2), max(k1, ok1));
            k1 = min(k1, ok1);
        }
        if (lr == 0) {
            int px = px0 + (r >> 2) * 16 + lg * 4 + (r & 3);
            int o = quarter * NPIX + px;
            hv1[o] = bitsf(k1 & 0xFFFFFC00u);   // biased by +2048; bias cancels in gaps
            hv2[o] = bitsf(k2 & 0xFFFFFC00u);
            hidx[o] = (int)(k1 & 1023u);
        }
    }
}

// -------- merge the four K-quarters, write idx, flag near-ties --------
__global__ void merge_quarters(const float* __restrict__ hv1, const float* __restrict__ hv2,
                               const int* __restrict__ hidx, int* __restrict__ idx_out,
                               int* __restrict__ worklist, int* __restrict__ wcount) {
    int px = blockIdx.x * 256 + threadIdx.x;
    float v1 = hv1[px], v2 = hv2[px];
    int   i1 = hidx[px];
#pragma unroll
    for (int q = 1; q < 4; ++q) {
        float va = hv1[q * NPIX + px];
        float sa = hv2[q * NPIX + px];
        int   ia = hidx[q * NPIX + px];
        if (va < v1) {               // ascending-quarter order keeps lowest idx on ties
            v2 = fminf(v1, sa);
            v1 = va; i1 = ia;
        } else {
            v2 = fminf(v2, va);
        }
    }
    idx_out[px] = i1;
    if (v2 - v1 < TAU) {
        int pos = atomicAdd(wcount, 1);
        worklist[pos] = px;
    }
}

// -------- exact fp32 rescore: RB px/block, thread t owns codes 4t..4t+3 --------
__launch_bounds__(256)
__global__ void vq_rescue(const float* __restrict__ x, const float* __restrict__ embed,
                          const float* __restrict__ ee,
                          const int* __restrict__ worklist, const int* __restrict__ wcount,
                          int* __restrict__ idx_out) {
    __shared__ float xs[RB][CDIM];
    __shared__ int   pxs[RB];
    __shared__ float redv[4][RB];
    __shared__ int   redi[4][RB];
    const int t  = threadIdx.x;
    const int wv = t >> 6, ln = t & 63;
    const int cnt = *wcount;
    for (int base = blockIdx.x * RB; base < cnt; base += gridDim.x * RB) {
        const int nb = min(RB, cnt - base);
        __syncthreads();
        if (t < RB) pxs[t] = worklist[base + (t < nb ? t : nb - 1)];
        __syncthreads();
#pragma unroll
        for (int i = 0; i < RB; ++i) {
            int gn = pxs[i];
            xs[i][t] = x[(size_t)(gn >> 10) * CDIM * HW + (size_t)t * HW + (gn & 1023)];
        }
        __syncthreads();

        float4 acc[RB];
#pragma unroll
        for (int i = 0; i < RB; ++i) acc[i] = make_float4(0.f, 0.f, 0.f, 0.f);
#pragma unroll 4
        for (int c = 0; c < CDIM; ++c) {
            float4 ev = *(const float4*)&embed[c * KDIM + t * 4];
#pragma unroll
            for (int i = 0; i < RB; ++i) {
                float xv = xs[i][c];
                acc[i].x = fmaf(xv, ev.x, acc[i].x);
                acc[i].y = fmaf(xv, ev.y, acc[i].y);
                acc[i].z = fmaf(xv, ev.z, acc[i].z);
                acc[i].w = fmaf(xv, ev.w, acc[i].w);
            }
        }
        const float4 eev = *(const float4*)&ee[t * 4];
#pragma unroll
        for (int i = 0; i < RB; ++i) {
            float d0 = fmaf(-2.f, acc[i].x, eev.x);
            float d1 = fmaf(-2.f, acc[i].y, eev.y);
            float d2 = fmaf(-2.f, acc[i].z, eev.z);
            float d3 = fmaf(-2.f, acc[i].w, eev.w);
            float v = d0; int ix = t * 4;
            if (d1 < v) { v = d1; ix = t * 4 + 1; }
            if (d2 < v) { v = d2; ix = t * 4 + 2; }
            if (d3 < v) { v = d3; ix = t * 4 + 3; }
#pragma unroll
            for (int mask = 1; mask < 64; mask <<= 1) {
                float ov = __shfl_xor(v, mask, 64);
                int   oi = __shfl_xor(ix, mask, 64);
                bool take = (ov < v) || (ov == v && oi < ix);
                v = take ? ov : v; ix = take ? oi : ix;
            }
            if (ln == 0) { redv[wv][i] = v; redi[wv][i] = ix; }
        }
        __syncthreads();
        if (t < nb) {
            float fv = redv[0][t]; int fi = redi[0][t];
#pragma unroll
            for (int q = 1; q < 4; ++q) {
                float v = redv[q][t]; int ix = redi[q][t];
                if (v < fv || (v == fv && ix < fi)) { fv = v; fi = ix; }
            }
            idx_out[pxs[t]] = fi;
        }
    }
}

// -------- epilogue: 128 px/block in 2 LDS passes; idx snapshot BEFORE overwrite --------
__launch_bounds__(256)
__global__ void vq_epilogue(const float* __restrict__ x, const float* __restrict__ embed,
                            const float* __restrict__ embedT, int useT,
                            const int* __restrict__ idx_in, float* __restrict__ out_q,
                            float* __restrict__ out_idx, float* __restrict__ partials) {
    __shared__ float q[16384];
    __shared__ int   idxs[128];
    __shared__ float lred[4];
    const int t = threadIdx.x;
    const int w = t >> 6, l = t & 63;
    const int n0 = blockIdx.x * 128;
    const int b  = n0 >> 10;

    if (t < 128) idxs[t] = idx_in[n0 + t];
    __syncthreads();
    if (t < 128) out_idx[n0 + t] = (float)idxs[t];

    const int j  = t >> 2;
    const int qd = t & 3;
    float lsum = 0.f;

#pragma unroll
    for (int pass = 0; pass < 2; ++pass) {
        const int myidx = idxs[pass * 64 + j];
        if (useT) {
            const float4* src4 = (const float4*)embedT + (size_t)myidx * 64;
#pragma unroll
            for (int i = 0; i < 16; ++i) {
                float4 v = src4[qd * 16 + i];
                int c = qd * 64 + i * 4;
                q[(c + 0) * 64 + (j ^ SWZ(c + 0))] = v.x;
                q[(c + 1) * 64 + (j ^ SWZ(c + 1))] = v.y;
                q[(c + 2) * 64 + (j ^ SWZ(c + 2))] = v.z;
                q[(c + 3) * 64 + (j ^ SWZ(c + 3))] = v.w;
            }
        } else {
#pragma unroll 4
            for (int i = 0; i < 64; ++i) {
                int c = qd * 64 + i;
                q[c * 64 + (j ^ SWZ(c))] = embed[(size_t)c * KDIM + myidx];
            }
        }
        __syncthreads();

        const int p0 = (n0 & 1023) + pass * 64;
        const size_t xbase = (size_t)b * CDIM * HW + p0;
#pragma unroll 8
        for (int ci = 0; ci < 64; ++ci) {
            int c = w * 64 + ci;
            float qv = q[c * 64 + (l ^ SWZ(c))];
            float xv = x[xbase + (size_t)c * HW + l];
            out_q[xbase + (size_t)c * HW + l] = qv;
            float d = qv - xv;
            lsum = fmaf(d, d, lsum);
        }
        __syncthreads();
    }

#pragma unroll
    for (int off = 32; off > 0; off >>= 1)
        lsum += __shfl_down(lsum, off, 64);
    if (l == 0) lred[w] = lsum;
    __syncthreads();
    if (t == 0)
        partials[blockIdx.x] = (lred[0] + lred[1]) + (lred[2] + lred[3]);
}

__global__ void loss_kernel(const float* __restrict__ partials, float* __restrict__ out_loss) {
    __shared__ float s[256];
    s[threadIdx.x] = partials[threadIdx.x] + partials[threadIdx.x + 256];
    __syncthreads();
    for (int off = 128; off > 0; off >>= 1) {
        if (threadIdx.x < off) s[threadIdx.x] += s[threadIdx.x + off];
        __syncthreads();
    }
    if (threadIdx.x == 0)
        out_loss[0] = 1.25f * s[0] / 16777216.0f;
}

extern "C" void kernel_launch(void* const* d_in, const int* in_sizes, int n_in,
                              void* d_out, int out_size, void* d_ws, size_t ws_size,
                              hipStream_t stream) {
    const float* x     = (const float*)d_in[0];
    const float* embed = (const float*)d_in[1];
    float* out_q    = (float*)d_out;
    float* out_loss = out_q + (size_t)NPIX * CDIM;
    float* out_idx  = out_loss + 1;
    int*   idx_i32  = (int*)out_idx;

    // scratch inside out_q region (all consumed before epilogue writes)
    short* e_hi     = (short*)out_q;                  // 512 KB (131072 floats)
    int*   worklist = (int*)(out_q + 131072);         // 65536 ints
    float* hv1      = out_q + 196608;                 // 4 x 64K floats
    float* hv2      = out_q + 458752;                 // 4 x 64K floats
    int*   hidx     = (int*)(out_q + 720896);         // 4 x 64K ints

    // d_ws: small proven budget; embedT behind ws_size guard
    float* ws       = (float*)d_ws;
    float* ee       = ws;                             // 1024 floats
    float* eeb      = ws + 1024;                      // 1024 floats (ee + 2048)
    int*   wcount   = (int*)(ws + 2048);
    float* partials = ws + 2112;                      // 512 floats
    float* embedT   = ws + 2624;                      // 262144 floats (1 MB), guarded
    int useT = (ws_size >= (size_t)(2624 + 262144) * sizeof(float)) ? 1 : 0;

    ee_kernel<<<KDIM / 256, 256, 0, stream>>>(embed, ee, eeb);
    if (useT) transpose_e<<<256, 256, 0, stream>>>(embed, embedT);
    prep_e<<<128, 256, 0, stream>>>(embed, e_hi);
    hipMemsetAsync(wcount, 0, 4, stream);
    vq_gemm<<<2048, 256, 0, stream>>>(x, e_hi, eeb, hv1, hv2, hidx);
    merge_quarters<<<NPIX / 256, 256, 0, stream>>>(hv1, hv2, hidx, idx_i32, worklist, wcount);
    vq_rescue<<<1024, 256, 0, stream>>>(x, embed, ee, worklist, wcount, idx_i32);
    vq_epilogue<<<NPIX / 128, 256, 0, stream>>>(x, embed, useT ? embedT : embed, useT,
                                                idx_i32, out_q, out_idx, partials);
    loss_kernel<<<1, 256, 0, stream>>>(partials, out_loss);
}

// Round 12
// 181.140 us; speedup vs baseline: 1.1337x; 1.1337x over previous
//
#include <hip/hip_runtime.h>

#define CDIM 256
#define HW   1024
#define NPIX 65536
#define KDIM 1024
#define TAU  0.5f
#define RB   8
#define SWZ(c) (((c) & 31) ^ (((c) >> 3) & 24))

using bf16x8 = __attribute__((ext_vector_type(8))) short;
using f32x4  = __attribute__((ext_vector_type(4))) float;
typedef unsigned int u32;

static __device__ __forceinline__ unsigned short f2bf(float v) {
    union { float f; unsigned u; } a; a.f = v;
    unsigned u = a.u;
    u += 0x7fffu + ((u >> 16) & 1u);   // RTN
    return (unsigned short)(u >> 16);
}

static __device__ __forceinline__ void gload_lds16(const void* g, void* s) {
    __builtin_amdgcn_global_load_lds(
        (const __attribute__((address_space(1))) u32*)g,
        (__attribute__((address_space(3))) u32*)s,
        16, 0, 0);
}

// -------- ee[k] = sum_c embed[c][k]^2 (exact fp32) --------
__global__ void ee_kernel(const float* __restrict__ embed, float* __restrict__ ee) {
    int k = blockIdx.x * 256 + threadIdx.x;
    float s = 0.f;
#pragma unroll 8
    for (int c = 0; c < CDIM; ++c) {
        float v = embed[c * KDIM + k];
        s += v * v;
    }
    ee[k] = s;
}

// -------- embedT[k][c] = embed[c][k] (fp32 transpose, 32x32 LDS tiles) --------
__global__ void transpose_e(const float* __restrict__ embed, float* __restrict__ embedT) {
    __shared__ float tl[32][33];
    const int t = threadIdx.x;
    const int j = t & 31, r = t >> 5;
    const int k0 = (blockIdx.x & 31) * 32;
    const int c0 = (blockIdx.x >> 5) * 32;
#pragma unroll
    for (int rr = 0; rr < 4; ++rr) {
        int c = r * 4 + rr;
        tl[c][j] = embed[(size_t)(c0 + c) * KDIM + k0 + j];
    }
    __syncthreads();
#pragma unroll
    for (int rr = 0; rr < 4; ++rr) {
        int k = r * 4 + rr;
        embedT[(size_t)(k0 + k) * CDIM + c0 + j] = tl[j][k];
    }
}

// -------- bf16(-2*embed) in MFMA B-fragment order --------
// frag f = ((nt*2+nh)*8 + ks)*4 + nf; lane l elem j:
//   B[k = ks*32 + (l>>4)*8 + j][n = nt*128 + (nh*4+nf)*16 + (l&15)]
__global__ void prep_e(const float* __restrict__ embed, short* __restrict__ e_hi) {
    int tid = blockIdx.x * 256 + threadIdx.x;   // 32768
    int l  = tid & 63;
    int f  = tid >> 6;            // 0..511
    int nf = f & 3;
    int ks = (f >> 2) & 7;
    int nh = (f >> 5) & 1;
    int nt = f >> 6;
    int n  = nt * 128 + (nh * 4 + nf) * 16 + (l & 15);
    int c0 = ks * 32 + (l >> 4) * 8;
    bf16x8 h8;
#pragma unroll
    for (int j = 0; j < 8; ++j)
        h8[j] = (short)f2bf(-2.0f * embed[(c0 + j) * KDIM + n]);
    *(bf16x8*)&e_hi[(size_t)tid * 8] = h8;
}

// -------- main screen: 128-px tiles (32 px/wave), K-split x4 (HIGH bits), exact gaps --------
__launch_bounds__(256, 3)
__global__ void vq_gemm(const float* __restrict__ x, const short* __restrict__ e_hi,
                        const float* __restrict__ ee,
                        float* __restrict__ hv1, float* __restrict__ hv2,
                        int* __restrict__ hidx) {
    __shared__ short Bs[2][8192];    // 2 x 16 KB (32 codes x 256 ch)
    const int t  = threadIdx.x;
    const int l  = t & 63;
    const int w  = t >> 6;
    const int lr = l & 15;
    const int lg = l >> 4;
    const int tile    = blockIdx.x & 511;       // 0..511 (128-px tiles)
    const int quarter = blockIdx.x >> 9;        // HIGH bits: stride 512 % 8 == 0 -> same XCD
    const int px0 = tile * 128 + w * 32;        // wave's 32 pixels
    const int b   = px0 >> 10;
    const int p0  = px0 & 1023;
    const float* xb = x + (size_t)b * CDIM * HW;

    const int c_first = quarter * 8;
    // stage chunk c slab s=w*4+i: src frag = ((c>>2)*2+((c>>1)&1))*32 + (c&1)*2 + (s>>1)*4 + (s&1)
    {
        const int slab = w * 4;
        const char* srcb = (const char*)e_hi +
            (size_t)(((c_first >> 2) * 2 + ((c_first >> 1) & 1)) * 32 + (c_first & 1) * 2) * 1024 + l * 16;
        char* dstb = (char*)&Bs[0][0] + (size_t)slab * 1024 + l * 16;
#pragma unroll
        for (int i = 0; i < 4; ++i) {
            int s = slab + i;
            gload_lds16(srcb + (size_t)((s >> 1) * 4 + (s & 1)) * 1024, dstb + (size_t)i * 1024);
        }
    }

    // ---- load + convert A fragments (32 px x 256 ch -> 16 frags = 64 VGPR) ----
    bf16x8 a[2][8];
#pragma unroll
    for (int mf = 0; mf < 2; ++mf) {
#pragma unroll
        for (int ks = 0; ks < 8; ++ks) {
            const float* p = xb + (size_t)(ks * 32 + lg * 8) * HW + p0 + mf * 16 + lr;
            float v[8];
#pragma unroll
            for (int j = 0; j < 8; ++j) v[j] = p[(size_t)j * HW];
#pragma unroll
            for (int j = 0; j < 8; ++j) a[mf][ks][j] = (short)f2bf(v[j]);
        }
    }

    float minv[8], min2v[8];
    int   mini[8];
#pragma unroll
    for (int r = 0; r < 8; ++r) { minv[r] = 3.4e38f; min2v[r] = 3.4e38f; mini[r] = 0; }

    __syncthreads();   // chunk 0 staged

    for (int cc = 0; cc < 8; ++cc) {
        const int c   = c_first + cc;
        const int cur = cc & 1;
        if (cc < 7) {   // prefetch next chunk into the other buffer
            const int cn = c + 1;
            const int slab = w * 4;
            const char* srcb = (const char*)e_hi +
                (size_t)(((cn >> 2) * 2 + ((cn >> 1) & 1)) * 32 + (cn & 1) * 2) * 1024 + l * 16;
            char* dstb = (char*)&Bs[cur ^ 1][0] + (size_t)slab * 1024 + l * 16;
#pragma unroll
            for (int i = 0; i < 4; ++i) {
                int s = slab + i;
                gload_lds16(srcb + (size_t)((s >> 1) * 4 + (s & 1)) * 1024, dstb + (size_t)i * 1024);
            }
        }

        f32x4 acc[2][2];
#pragma unroll
        for (int mf = 0; mf < 2; ++mf)
#pragma unroll
            for (int nfi = 0; nfi < 2; ++nfi)
                acc[mf][nfi] = (f32x4){0.f, 0.f, 0.f, 0.f};

#pragma unroll
        for (int ks = 0; ks < 8; ++ks) {
#pragma unroll
            for (int nfi = 0; nfi < 2; ++nfi) {
                bf16x8 bh = *(const bf16x8*)&Bs[cur][((ks * 2 + nfi) * 64 + l) * 8];
#pragma unroll
                for (int mf = 0; mf < 2; ++mf)
                    acc[mf][nfi] = __builtin_amdgcn_mfma_f32_16x16x32_bf16(a[mf][ks], bh, acc[mf][nfi], 0, 0, 0);
            }
        }

        // fold chunk into running (min, argmin, second-min) — exact floats
#pragma unroll
        for (int nfi = 0; nfi < 2; ++nfi) {
            const int kg = c * 32 + nfi * 16 + lr;
            const float eev = ee[kg];
#pragma unroll
            for (int mf = 0; mf < 2; ++mf)
#pragma unroll
                for (int j = 0; j < 4; ++j) {
                    const int r = mf * 4 + j;
                    float m = acc[mf][nfi][j] + eev;
                    bool lt = m < minv[r];
                    float sec = lt ? minv[r] : m;
                    minv[r] = lt ? m : minv[r];
                    mini[r] = lt ? kg : mini[r];
                    min2v[r] = fminf(min2v[r], sec);
                }
        }
        __syncthreads();   // next chunk landed + buffer swap
    }

    // ---- reduce across the 16 lanes (lr) sharing each pixel row ----
#pragma unroll
    for (int r = 0; r < 8; ++r) {
        float v1 = minv[r]; int i1 = mini[r]; float v2 = min2v[r];
#pragma unroll
        for (int mask = 1; mask < 16; mask <<= 1) {
            float ov1 = __shfl_xor(v1, mask, 64);
            int   oi1 = __shfl_xor(i1, mask, 64);
            float ov2 = __shfl_xor(v2, mask, 64);
            float vmax = fmaxf(v1, ov1);
            v2 = fminf(fminf(v2, ov2), vmax);
            bool take = (ov1 < v1) || (ov1 == v1 && oi1 < i1);
            v1 = take ? ov1 : v1;
            i1 = take ? oi1 : i1;
        }
        if (lr == 0) {
            int px = px0 + (r >> 2) * 16 + lg * 4 + (r & 3);
            int o = quarter * NPIX + px;
            hv1[o] = v1; hv2[o] = v2; hidx[o] = i1;
        }
    }
}

// -------- merge the four K-quarters, write idx, flag near-ties --------
__global__ void merge_quarters(const float* __restrict__ hv1, const float* __restrict__ hv2,
                               const int* __restrict__ hidx, int* __restrict__ idx_out,
                               int* __restrict__ worklist, int* __restrict__ wcount) {
    int px = blockIdx.x * 256 + threadIdx.x;
    float v1 = hv1[px], v2 = hv2[px];
    int   i1 = hidx[px];
#pragma unroll
    for (int q = 1; q < 4; ++q) {
        float va = hv1[q * NPIX + px];
        float sa = hv2[q * NPIX + px];
        int   ia = hidx[q * NPIX + px];
        if (va < v1) {               // ascending-quarter order keeps lowest idx on ties
            v2 = fminf(v1, sa);
            v1 = va; i1 = ia;
        } else {
            v2 = fminf(v2, va);
        }
    }
    idx_out[px] = i1;
    if (v2 - v1 < TAU) {
        int pos = atomicAdd(wcount, 1);
        worklist[pos] = px;
    }
}

// -------- exact fp32 rescore: RB=8 px/block, thread t owns codes 4t..4t+3 --------
__launch_bounds__(256)
__global__ void vq_rescue(const float* __restrict__ x, const float* __restrict__ embed,
                          const float* __restrict__ ee,
                          const int* __restrict__ worklist, const int* __restrict__ wcount,
                          int* __restrict__ idx_out) {
    __shared__ float xs[RB][CDIM];
    __shared__ int   pxs[RB];
    __shared__ float redv[4][RB];
    __shared__ int   redi[4][RB];
    const int t  = threadIdx.x;
    const int wv = t >> 6, ln = t & 63;
    const int cnt = *wcount;
    for (int base = blockIdx.x * RB; base < cnt; base += gridDim.x * RB) {
        const int nb = min(RB, cnt - base);
        __syncthreads();
        if (t < RB) pxs[t] = worklist[base + (t < nb ? t : nb - 1)];
        __syncthreads();
#pragma unroll
        for (int i = 0; i < RB; ++i) {
            int gn = pxs[i];
            xs[i][t] = x[(size_t)(gn >> 10) * CDIM * HW + (size_t)t * HW + (gn & 1023)];
        }
        __syncthreads();

        float4 acc[RB];
#pragma unroll
        for (int i = 0; i < RB; ++i) acc[i] = make_float4(0.f, 0.f, 0.f, 0.f);
#pragma unroll 4
        for (int c = 0; c < CDIM; ++c) {
            float4 ev = *(const float4*)&embed[c * KDIM + t * 4];
#pragma unroll
            for (int i = 0; i < RB; ++i) {
                float xv = xs[i][c];
                acc[i].x = fmaf(xv, ev.x, acc[i].x);
                acc[i].y = fmaf(xv, ev.y, acc[i].y);
                acc[i].z = fmaf(xv, ev.z, acc[i].z);
                acc[i].w = fmaf(xv, ev.w, acc[i].w);
            }
        }
        const float4 eev = *(const float4*)&ee[t * 4];
#pragma unroll
        for (int i = 0; i < RB; ++i) {
            float d0 = fmaf(-2.f, acc[i].x, eev.x);
            float d1 = fmaf(-2.f, acc[i].y, eev.y);
            float d2 = fmaf(-2.f, acc[i].z, eev.z);
            float d3 = fmaf(-2.f, acc[i].w, eev.w);
            float v = d0; int ix = t * 4;
            if (d1 < v) { v = d1; ix = t * 4 + 1; }
            if (d2 < v) { v = d2; ix = t * 4 + 2; }
            if (d3 < v) { v = d3; ix = t * 4 + 3; }
#pragma unroll
            for (int mask = 1; mask < 64; mask <<= 1) {
                float ov = __shfl_xor(v, mask, 64);
                int   oi = __shfl_xor(ix, mask, 64);
                bool take = (ov < v) || (ov == v && oi < ix);
                v = take ? ov : v; ix = take ? oi : ix;
            }
            if (ln == 0) { redv[wv][i] = v; redi[wv][i] = ix; }
        }
        __syncthreads();
        if (t < nb) {
            float fv = redv[0][t]; int fi = redi[0][t];
#pragma unroll
            for (int q = 1; q < 4; ++q) {
                float v = redv[q][t]; int ix = redi[q][t];
                if (v < fv || (v == fv && ix < fi)) { fv = v; fi = ix; }
            }
            idx_out[pxs[t]] = fi;
        }
    }
}

// -------- epilogue: 128 px/block in 2 LDS passes; idx snapshot BEFORE overwrite --------
__launch_bounds__(256)
__global__ void vq_epilogue(const float* __restrict__ x, const float* __restrict__ embed,
                            const float* __restrict__ embedT, int useT,
                            const int* __restrict__ idx_in, float* __restrict__ out_q,
                            float* __restrict__ out_idx, float* __restrict__ partials) {
    __shared__ float q[16384];
    __shared__ int   idxs[128];
    __shared__ float lred[4];
    const int t = threadIdx.x;
    const int w = t >> 6, l = t & 63;
    const int n0 = blockIdx.x * 128;
    const int b  = n0 >> 10;

    if (t < 128) idxs[t] = idx_in[n0 + t];
    __syncthreads();
    if (t < 128) out_idx[n0 + t] = (float)idxs[t];

    const int j  = t >> 2;
    const int qd = t & 3;
    float lsum = 0.f;

#pragma unroll
    for (int pass = 0; pass < 2; ++pass) {
        const int myidx = idxs[pass * 64 + j];
        if (useT) {
            const float4* src4 = (const float4*)embedT + (size_t)myidx * 64;
#pragma unroll
            for (int i = 0; i < 16; ++i) {
                float4 v = src4[qd * 16 + i];
                int c = qd * 64 + i * 4;
                q[(c + 0) * 64 + (j ^ SWZ(c + 0))] = v.x;
                q[(c + 1) * 64 + (j ^ SWZ(c + 1))] = v.y;
                q[(c + 2) * 64 + (j ^ SWZ(c + 2))] = v.z;
                q[(c + 3) * 64 + (j ^ SWZ(c + 3))] = v.w;
            }
        } else {
#pragma unroll 4
            for (int i = 0; i < 64; ++i) {
                int c = qd * 64 + i;
                q[c * 64 + (j ^ SWZ(c))] = embed[(size_t)c * KDIM + myidx];
            }
        }
        __syncthreads();

        const int p0 = (n0 & 1023) + pass * 64;
        const size_t xbase = (size_t)b * CDIM * HW + p0;
#pragma unroll 8
        for (int ci = 0; ci < 64; ++ci) {
            int c = w * 64 + ci;
            float qv = q[c * 64 + (l ^ SWZ(c))];
            float xv = x[xbase + (size_t)c * HW + l];
            out_q[xbase + (size_t)c * HW + l] = qv;
            float d = qv - xv;
            lsum = fmaf(d, d, lsum);
        }
        __syncthreads();
    }

#pragma unroll
    for (int off = 32; off > 0; off >>= 1)
        lsum += __shfl_down(lsum, off, 64);
    if (l == 0) lred[w] = lsum;
    __syncthreads();
    if (t == 0)
        partials[blockIdx.x] = (lred[0] + lred[1]) + (lred[2] + lred[3]);
}

__global__ void loss_kernel(const float* __restrict__ partials, float* __restrict__ out_loss) {
    __shared__ float s[256];
    s[threadIdx.x] = partials[threadIdx.x] + partials[threadIdx.x + 256];
    __syncthreads();
    for (int off = 128; off > 0; off >>= 1) {
        if (threadIdx.x < off) s[threadIdx.x] += s[threadIdx.x + off];
        __syncthreads();
    }
    if (threadIdx.x == 0)
        out_loss[0] = 1.25f * s[0] / 16777216.0f;
}

extern "C" void kernel_launch(void* const* d_in, const int* in_sizes, int n_in,
                              void* d_out, int out_size, void* d_ws, size_t ws_size,
                              hipStream_t stream) {
    const float* x     = (const float*)d_in[0];
    const float* embed = (const float*)d_in[1];
    float* out_q    = (float*)d_out;
    float* out_loss = out_q + (size_t)NPIX * CDIM;
    float* out_idx  = out_loss + 1;
    int*   idx_i32  = (int*)out_idx;

    // scratch inside out_q region (all consumed before epilogue writes)
    short* e_hi     = (short*)out_q;                  // 512 KB (131072 floats)
    int*   worklist = (int*)(out_q + 131072);         // 65536 ints
    float* hv1      = out_q + 196608;                 // 4 x 64K floats
    float* hv2      = out_q + 458752;                 // 4 x 64K floats
    int*   hidx     = (int*)(out_q + 720896);         // 4 x 64K ints

    // d_ws: small proven budget; embedT behind ws_size guard
    float* ws       = (float*)d_ws;
    float* ee       = ws;                             // 1024 floats
    int*   wcount   = (int*)(ws + 1024);
    float* partials = ws + 1088;                      // 512 floats
    float* embedT   = ws + 1600;                      // 262144 floats (1 MB), guarded
    int useT = (ws_size >= (size_t)(1600 + 262144) * sizeof(float)) ? 1 : 0;

    ee_kernel<<<KDIM / 256, 256, 0, stream>>>(embed, ee);
    if (useT) transpose_e<<<256, 256, 0, stream>>>(embed, embedT);
    prep_e<<<128, 256, 0, stream>>>(embed, e_hi);
    hipMemsetAsync(wcount, 0, 4, stream);
    vq_gemm<<<2048, 256, 0, stream>>>(x, e_hi, ee, hv1, hv2, hidx);
    merge_quarters<<<NPIX / 256, 256, 0, stream>>>(hv1, hv2, hidx, idx_i32, worklist, wcount);
    vq_rescue<<<2048, 256, 0, stream>>>(x, embed, ee, worklist, wcount, idx_i32);
    vq_epilogue<<<NPIX / 128, 256, 0, stream>>>(x, embed, useT ? embedT : embed, useT,
                                                idx_i32, out_q, out_idx, partials);
    loss_kernel<<<1, 256, 0, stream>>>(partials, out_loss);
}

// Round 13
// 171.312 us; speedup vs baseline: 1.1988x; 1.0574x over previous
//
#include <hip/hip_runtime.h>

#define CDIM 256
#define HW   1024
#define NPIX 65536
#define KDIM 1024
#define TAU  0.5f
#define RB   8
#define SWZ(c) (((c) & 31) ^ (((c) >> 3) & 24))

using bf16x8 = __attribute__((ext_vector_type(8))) short;
using f32x4  = __attribute__((ext_vector_type(4))) float;
typedef unsigned int u32;

static __device__ __forceinline__ unsigned short f2bf(float v) {
    union { float f; unsigned u; } a; a.f = v;
    unsigned u = a.u;
    u += 0x7fffu + ((u >> 16) & 1u);   // RTN
    return (unsigned short)(u >> 16);
}

static __device__ __forceinline__ void gload_lds16(const void* g, void* s) {
    __builtin_amdgcn_global_load_lds(
        (const __attribute__((address_space(1))) u32*)g,
        (__attribute__((address_space(3))) u32*)s,
        16, 0, 0);
}

// -------- ee[k] = sum_c embed[c][k]^2 (exact fp32) --------
__global__ void ee_kernel(const float* __restrict__ embed, float* __restrict__ ee) {
    int k = blockIdx.x * 256 + threadIdx.x;
    float s = 0.f;
#pragma unroll 8
    for (int c = 0; c < CDIM; ++c) {
        float v = embed[c * KDIM + k];
        s += v * v;
    }
    ee[k] = s;
}

// -------- embedT[k][c] = embed[c][k] (fp32 transpose, 32x32 LDS tiles) --------
__global__ void transpose_e(const float* __restrict__ embed, float* __restrict__ embedT) {
    __shared__ float tl[32][33];
    const int t = threadIdx.x;
    const int j = t & 31, r = t >> 5;
    const int k0 = (blockIdx.x & 31) * 32;
    const int c0 = (blockIdx.x >> 5) * 32;
#pragma unroll
    for (int rr = 0; rr < 4; ++rr) {
        int c = r * 4 + rr;
        tl[c][j] = embed[(size_t)(c0 + c) * KDIM + k0 + j];
    }
    __syncthreads();
#pragma unroll
    for (int rr = 0; rr < 4; ++rr) {
        int k = r * 4 + rr;
        embedT[(size_t)(k0 + k) * CDIM + c0 + j] = tl[j][k];
    }
}

// -------- bf16(-2*embed) in MFMA B-fragment order --------
// frag f = ((nt*2+nh)*8 + ks)*4 + nf; lane l elem j:
//   B[k = ks*32 + (l>>4)*8 + j][n = nt*128 + (nh*4+nf)*16 + (l&15)]
__global__ void prep_e(const float* __restrict__ embed, short* __restrict__ e_hi) {
    int tid = blockIdx.x * 256 + threadIdx.x;   // 32768
    int l  = tid & 63;
    int f  = tid >> 6;            // 0..511
    int nf = f & 3;
    int ks = (f >> 2) & 7;
    int nh = (f >> 5) & 1;
    int nt = f >> 6;
    int n  = nt * 128 + (nh * 4 + nf) * 16 + (l & 15);
    int c0 = ks * 32 + (l >> 4) * 8;
    bf16x8 h8;
#pragma unroll
    for (int j = 0; j < 8; ++j)
        h8[j] = (short)f2bf(-2.0f * embed[(c0 + j) * KDIM + n]);
    *(bf16x8*)&e_hi[(size_t)tid * 8] = h8;
}

// -------- main screen: FULL K per block; 128 px/block (32 px/wave); 32 chunks --------
__launch_bounds__(256, 2)
__global__ void vq_gemm(const float* __restrict__ x, const short* __restrict__ e_hi,
                        const float* __restrict__ ee, int* __restrict__ idx_out,
                        int* __restrict__ worklist, int* __restrict__ wcount) {
    __shared__ short Bs[2][8192];    // 2 x 16 KB (32 codes x 256 ch)
    const int t  = threadIdx.x;
    const int l  = t & 63;
    const int w  = t >> 6;
    const int lr = l & 15;
    const int lg = l >> 4;
    const int px0 = blockIdx.x * 128 + w * 32;  // wave's 32 pixels
    const int b   = px0 >> 10;
    const int p0  = px0 & 1023;
    const float* xb = x + (size_t)b * CDIM * HW;

    // stage chunk 0: slab s = w*4+i; src frag = ((c>>2)*2+((c>>1)&1))*32 + (c&1)*2 + (s>>1)*4 + (s&1)
    {
        const int slab = w * 4;
        const char* srcb = (const char*)e_hi + (size_t)l * 16;   // chunk 0 base
        char* dstb = (char*)&Bs[0][0] + (size_t)slab * 1024 + l * 16;
#pragma unroll
        for (int i = 0; i < 4; ++i) {
            int s = slab + i;
            gload_lds16(srcb + (size_t)((s >> 1) * 4 + (s & 1)) * 1024, dstb + (size_t)i * 1024);
        }
    }

    // ---- load + convert A fragments (32 px x 256 ch -> 16 frags = 64 VGPR) ----
    bf16x8 a[2][8];
#pragma unroll
    for (int mf = 0; mf < 2; ++mf) {
#pragma unroll
        for (int ks = 0; ks < 8; ++ks) {
            const float* p = xb + (size_t)(ks * 32 + lg * 8) * HW + p0 + mf * 16 + lr;
            float v[8];
#pragma unroll
            for (int j = 0; j < 8; ++j) v[j] = p[(size_t)j * HW];
#pragma unroll
            for (int j = 0; j < 8; ++j) a[mf][ks][j] = (short)f2bf(v[j]);
        }
    }

    float minv[8], min2v[8];
    int   mini[8];
#pragma unroll
    for (int r = 0; r < 8; ++r) { minv[r] = 3.4e38f; min2v[r] = 3.4e38f; mini[r] = 0; }

    __syncthreads();   // chunk 0 staged

    for (int c = 0; c < 32; ++c) {
        const int cur = c & 1;
        if (c < 31) {   // prefetch next chunk into the other buffer
            const int cn = c + 1;
            const int slab = w * 4;
            const char* srcb = (const char*)e_hi +
                (size_t)(((cn >> 2) * 2 + ((cn >> 1) & 1)) * 32 + (cn & 1) * 2) * 1024 + l * 16;
            char* dstb = (char*)&Bs[cur ^ 1][0] + (size_t)slab * 1024 + l * 16;
#pragma unroll
            for (int i = 0; i < 4; ++i) {
                int s = slab + i;
                gload_lds16(srcb + (size_t)((s >> 1) * 4 + (s & 1)) * 1024, dstb + (size_t)i * 1024);
            }
        }

        f32x4 acc[2][2];
#pragma unroll
        for (int mf = 0; mf < 2; ++mf)
#pragma unroll
            for (int nfi = 0; nfi < 2; ++nfi)
                acc[mf][nfi] = (f32x4){0.f, 0.f, 0.f, 0.f};

#pragma unroll
        for (int ks = 0; ks < 8; ++ks) {
#pragma unroll
            for (int nfi = 0; nfi < 2; ++nfi) {
                bf16x8 bh = *(const bf16x8*)&Bs[cur][((ks * 2 + nfi) * 64 + l) * 8];
#pragma unroll
                for (int mf = 0; mf < 2; ++mf)
                    acc[mf][nfi] = __builtin_amdgcn_mfma_f32_16x16x32_bf16(a[mf][ks], bh, acc[mf][nfi], 0, 0, 0);
            }
        }

        // fold chunk into running (min, argmin, second-min) — exact floats
#pragma unroll
        for (int nfi = 0; nfi < 2; ++nfi) {
            const int kg = c * 32 + nfi * 16 + lr;
            const float eev = ee[kg];
#pragma unroll
            for (int mf = 0; mf < 2; ++mf)
#pragma unroll
                for (int j = 0; j < 4; ++j) {
                    const int r = mf * 4 + j;
                    float m = acc[mf][nfi][j] + eev;
                    bool lt = m < minv[r];
                    float sec = lt ? minv[r] : m;
                    minv[r] = lt ? m : minv[r];
                    mini[r] = lt ? kg : mini[r];
                    min2v[r] = fminf(min2v[r], sec);
                }
        }
        __syncthreads();   // next chunk landed + buffer swap
    }

    // ---- reduce across the 16 lanes (lr) sharing each pixel row; final answer ----
#pragma unroll
    for (int r = 0; r < 8; ++r) {
        float v1 = minv[r]; int i1 = mini[r]; float v2 = min2v[r];
#pragma unroll
        for (int mask = 1; mask < 16; mask <<= 1) {
            float ov1 = __shfl_xor(v1, mask, 64);
            int   oi1 = __shfl_xor(i1, mask, 64);
            float ov2 = __shfl_xor(v2, mask, 64);
            float vmax = fmaxf(v1, ov1);
            v2 = fminf(fminf(v2, ov2), vmax);
            bool take = (ov1 < v1) || (ov1 == v1 && oi1 < i1);
            v1 = take ? ov1 : v1;
            i1 = take ? oi1 : i1;
        }
        if (lr == 0) {
            int px = px0 + (r >> 2) * 16 + lg * 4 + (r & 3);
            idx_out[px] = i1;
            if (v2 - v1 < TAU) {
                int pos = atomicAdd(wcount, 1);
                worklist[pos] = px;
            }
        }
    }
}

// -------- exact fp32 rescore: RB=8 px/block, thread t owns codes 4t..4t+3 --------
__launch_bounds__(256)
__global__ void vq_rescue(const float* __restrict__ x, const float* __restrict__ embed,
                          const float* __restrict__ ee,
                          const int* __restrict__ worklist, const int* __restrict__ wcount,
                          int* __restrict__ idx_out) {
    __shared__ float xs[RB][CDIM];
    __shared__ int   pxs[RB];
    __shared__ float redv[4][RB];
    __shared__ int   redi[4][RB];
    const int t  = threadIdx.x;
    const int wv = t >> 6, ln = t & 63;
    const int cnt = *wcount;
    for (int base = blockIdx.x * RB; base < cnt; base += gridDim.x * RB) {
        const int nb = min(RB, cnt - base);
        __syncthreads();
        if (t < RB) pxs[t] = worklist[base + (t < nb ? t : nb - 1)];
        __syncthreads();
#pragma unroll
        for (int i = 0; i < RB; ++i) {
            int gn = pxs[i];
            xs[i][t] = x[(size_t)(gn >> 10) * CDIM * HW + (size_t)t * HW + (gn & 1023)];
        }
        __syncthreads();

        float4 acc[RB];
#pragma unroll
        for (int i = 0; i < RB; ++i) acc[i] = make_float4(0.f, 0.f, 0.f, 0.f);
#pragma unroll 4
        for (int c = 0; c < CDIM; ++c) {
            float4 ev = *(const float4*)&embed[c * KDIM + t * 4];
#pragma unroll
            for (int i = 0; i < RB; ++i) {
                float xv = xs[i][c];
                acc[i].x = fmaf(xv, ev.x, acc[i].x);
                acc[i].y = fmaf(xv, ev.y, acc[i].y);
                acc[i].z = fmaf(xv, ev.z, acc[i].z);
                acc[i].w = fmaf(xv, ev.w, acc[i].w);
            }
        }
        const float4 eev = *(const float4*)&ee[t * 4];
#pragma unroll
        for (int i = 0; i < RB; ++i) {
            float d0 = fmaf(-2.f, acc[i].x, eev.x);
            float d1 = fmaf(-2.f, acc[i].y, eev.y);
            float d2 = fmaf(-2.f, acc[i].z, eev.z);
            float d3 = fmaf(-2.f, acc[i].w, eev.w);
            float v = d0; int ix = t * 4;
            if (d1 < v) { v = d1; ix = t * 4 + 1; }
            if (d2 < v) { v = d2; ix = t * 4 + 2; }
            if (d3 < v) { v = d3; ix = t * 4 + 3; }
#pragma unroll
            for (int mask = 1; mask < 64; mask <<= 1) {
                float ov = __shfl_xor(v, mask, 64);
                int   oi = __shfl_xor(ix, mask, 64);
                bool take = (ov < v) || (ov == v && oi < ix);
                v = take ? ov : v; ix = take ? oi : ix;
            }
            if (ln == 0) { redv[wv][i] = v; redi[wv][i] = ix; }
        }
        __syncthreads();
        if (t < nb) {
            float fv = redv[0][t]; int fi = redi[0][t];
#pragma unroll
            for (int q = 1; q < 4; ++q) {
                float v = redv[q][t]; int ix = redi[q][t];
                if (v < fv || (v == fv && ix < fi)) { fv = v; fi = ix; }
            }
            idx_out[pxs[t]] = fi;
        }
    }
}

// -------- epilogue: 128 px/block in 2 LDS passes; idx snapshot BEFORE overwrite --------
__launch_bounds__(256)
__global__ void vq_epilogue(const float* __restrict__ x, const float* __restrict__ embed,
                            const float* __restrict__ embedT, int useT,
                            const int* __restrict__ idx_in, float* __restrict__ out_q,
                            float* __restrict__ out_idx, float* __restrict__ partials) {
    __shared__ float q[16384];
    __shared__ int   idxs[128];
    __shared__ float lred[4];
    const int t = threadIdx.x;
    const int w = t >> 6, l = t & 63;
    const int n0 = blockIdx.x * 128;
    const int b  = n0 >> 10;

    if (t < 128) idxs[t] = idx_in[n0 + t];
    __syncthreads();
    if (t < 128) out_idx[n0 + t] = (float)idxs[t];

    const int j  = t >> 2;
    const int qd = t & 3;
    float lsum = 0.f;

#pragma unroll
    for (int pass = 0; pass < 2; ++pass) {
        const int myidx = idxs[pass * 64 + j];
        if (useT) {
            const float4* src4 = (const float4*)embedT + (size_t)myidx * 64;
#pragma unroll
            for (int i = 0; i < 16; ++i) {
                float4 v = src4[qd * 16 + i];
                int c = qd * 64 + i * 4;
                q[(c + 0) * 64 + (j ^ SWZ(c + 0))] = v.x;
                q[(c + 1) * 64 + (j ^ SWZ(c + 1))] = v.y;
                q[(c + 2) * 64 + (j ^ SWZ(c + 2))] = v.z;
                q[(c + 3) * 64 + (j ^ SWZ(c + 3))] = v.w;
            }
        } else {
#pragma unroll 4
            for (int i = 0; i < 64; ++i) {
                int c = qd * 64 + i;
                q[c * 64 + (j ^ SWZ(c))] = embed[(size_t)c * KDIM + myidx];
            }
        }
        __syncthreads();

        const int p0 = (n0 & 1023) + pass * 64;
        const size_t xbase = (size_t)b * CDIM * HW + p0;
#pragma unroll 8
        for (int ci = 0; ci < 64; ++ci) {
            int c = w * 64 + ci;
            float qv = q[c * 64 + (l ^ SWZ(c))];
            float xv = x[xbase + (size_t)c * HW + l];
            out_q[xbase + (size_t)c * HW + l] = qv;
            float d = qv - xv;
            lsum = fmaf(d, d, lsum);
        }
        __syncthreads();
    }

#pragma unroll
    for (int off = 32; off > 0; off >>= 1)
        lsum += __shfl_down(lsum, off, 64);
    if (l == 0) lred[w] = lsum;
    __syncthreads();
    if (t == 0)
        partials[blockIdx.x] = (lred[0] + lred[1]) + (lred[2] + lred[3]);
}

__global__ void loss_kernel(const float* __restrict__ partials, float* __restrict__ out_loss) {
    __shared__ float s[256];
    s[threadIdx.x] = partials[threadIdx.x] + partials[threadIdx.x + 256];
    __syncthreads();
    for (int off = 128; off > 0; off >>= 1) {
        if (threadIdx.x < off) s[threadIdx.x] += s[threadIdx.x + off];
        __syncthreads();
    }
    if (threadIdx.x == 0)
        out_loss[0] = 1.25f * s[0] / 16777216.0f;
}

extern "C" void kernel_launch(void* const* d_in, const int* in_sizes, int n_in,
                              void* d_out, int out_size, void* d_ws, size_t ws_size,
                              hipStream_t stream) {
    const float* x     = (const float*)d_in[0];
    const float* embed = (const float*)d_in[1];
    float* out_q    = (float*)d_out;
    float* out_loss = out_q + (size_t)NPIX * CDIM;
    float* out_idx  = out_loss + 1;
    int*   idx_i32  = (int*)out_idx;

    // scratch inside out_q region (all consumed before epilogue writes)
    short* e_hi     = (short*)out_q;                  // 512 KB (131072 floats)
    int*   worklist = (int*)(out_q + 131072);         // 65536 ints

    // d_ws: small proven budget; embedT behind ws_size guard
    float* ws       = (float*)d_ws;
    float* ee       = ws;                             // 1024 floats
    int*   wcount   = (int*)(ws + 1024);
    float* partials = ws + 1088;                      // 512 floats
    float* embedT   = ws + 1600;                      // 262144 floats (1 MB), guarded
    int useT = (ws_size >= (size_t)(1600 + 262144) * sizeof(float)) ? 1 : 0;

    ee_kernel<<<KDIM / 256, 256, 0, stream>>>(embed, ee);
    if (useT) transpose_e<<<256, 256, 0, stream>>>(embed, embedT);
    prep_e<<<128, 256, 0, stream>>>(embed, e_hi);
    hipMemsetAsync(wcount, 0, 4, stream);
    vq_gemm<<<NPIX / 128, 256, 0, stream>>>(x, e_hi, ee, idx_i32, worklist, wcount);
    vq_rescue<<<2048, 256, 0, stream>>>(x, embed, ee, worklist, wcount, idx_i32);
    vq_epilogue<<<NPIX / 128, 256, 0, stream>>>(x, embed, useT ? embedT : embed, useT,
                                                idx_i32, out_q, out_idx, partials);
    loss_kernel<<<1, 256, 0, stream>>>(partials, out_loss);
}